// Round 15
// baseline (4645.448 us; speedup 1.0000x reference)
//
#include <hip/hip_runtime.h>
#include <stdint.h>

#define B_ 64
#define T_ 512
#define D_ 1024
#define U_ 1024
#define G4_ 4096
#define M_ (B_ * T_)  // 32768
#define ZLD 65        // zbuf row stride (floats)

typedef unsigned short u16;
typedef float f32x4 __attribute__((ext_vector_type(4)));
typedef _Float16 f16x8 __attribute__((ext_vector_type(8)));
typedef unsigned short u16x4 __attribute__((ext_vector_type(4)));

__device__ __forceinline__ u16 f2h(float f) {
  union { _Float16 h; u16 u; } v; v.h = (_Float16)f; return v.u;
}
__device__ __forceinline__ float h2f(uint32_t u) {
  union { _Float16 h; u16 u; } v; v.u = (u16)u; return (float)v.h;
}
__device__ __forceinline__ float sigm(float x) { return 1.f / (1.f + __expf(-x)); }
__device__ __forceinline__ float tanhf_(float x) {
  x = fminf(12.f, fmaxf(-12.f, x));
  float e = __expf(2.f * x);
  return (e - 1.f) / (e + 1.f);
}

__device__ __forceinline__ void glds16(const void* g, void* l) {
  __builtin_amdgcn_global_load_lds(
      (const __attribute__((address_space(1))) uint32_t*)g,
      (__attribute__((address_space(3))) uint32_t*)l, 16, 0, 0);
}

// row-strided stager for the GEMM (XOR swizzle on global source, rule #21)
template <int R>
__device__ __forceinline__ void stage_tile(const char* gbase, long gs, char* lds, int tid) {
  const int lane = tid & 63, wid = tid >> 6;
#pragma unroll
  for (int j = wid; j < R / 8; j += 4) {
    const int row = j * 8 + (lane >> 3);
    const int lg = ((lane & 7) * 16) ^ ((row & 7) << 4);
    glds16(gbase + (long)row * gs + lg, lds + j * 1024);
  }
}

__device__ __forceinline__ f16x8 read_frag(const char* lds, int row, int kbyte) {
  const int ph = row * 128 + (kbyte ^ ((row & 7) << 4));
  return *(const f16x8*)(lds + ph);
}

#define MFMA_(a, b, c) __builtin_amdgcn_mfma_f32_16x16x32_f16(a, b, c, 0, 0, 0)

// ---------------- prep kernels ----------------

__global__ __launch_bounds__(256) void cast_x_kernel(const float* __restrict__ x,
                                                     u16* __restrict__ xb) {
  const long n = (long)M_ * D_ / 4;
  for (long i = (long)blockIdx.x * blockDim.x + threadIdx.x; i < n;
       i += (long)gridDim.x * blockDim.x) {
    f32x4 v = ((const f32x4*)x)[i];
    u16x4 r;
#pragma unroll
    for (int j = 0; j < 4; ++j) r[j] = f2h(v[j]);
    ((u16x4*)xb)[i] = r;
  }
}

// x-part weights, k-major 16-unit packing (GEMM B operand).
// p = ub*64 + g*16 + ui  <->  orig col = g*1024 + ub*16 + ui.
__global__ __launch_bounds__(256) void pack_wx_kernel(const float* __restrict__ Wf,
                                                      const float* __restrict__ Wb,
                                                      u16* __restrict__ wxT) {
  const int idx = blockIdx.x * 256 + threadIdx.x;  // 2*64*4096 = 2^19
  const int p = idx & 4095;
  const int kc = (idx >> 12) & 63;
  const int d = (idx >> 18) & 1;
  const float* W = d ? Wb : Wf;
  const int orig = ((p >> 4) & 3) * 1024 + ((p >> 6) << 4) + (p & 15);
  u16* dst = wxT + ((long)d * G4_ + p) * 1024 + kc * 16;
  const float* src = W + (long)(kc * 16) * G4_ + orig;
#pragma unroll
  for (int j = 0; j < 16; ++j) dst[j] = f2h(src[(long)j * G4_]);
}

// h-part weights, FRAGMENT-LINEAR: per (d, ub<64): 8 chunks x 16 frags x 1KB.
// frag f = ni*4 + kkl ; lane l elem j: col = ni*1024 + ub*16 + (l&15) [gate=ni]
//   k row = 1024 + cc*128 + kkl*32 + (l>>4)*8 + j
__global__ __launch_bounds__(256) void pack_whfl_kernel(const float* __restrict__ Wf,
                                                        const float* __restrict__ Wb,
                                                        u16* __restrict__ whfl) {
  const int idx = blockIdx.x * 256 + threadIdx.x;  // 2^20
  const int l = idx & 63;
  const int f = (idx >> 6) & 15;
  const int cc = (idx >> 10) & 7;
  const int ub = (idx >> 13) & 63;
  const int d = (idx >> 19) & 1;
  const float* W = d ? Wb : Wf;
  const int ni = f >> 2, kkl = f & 3;
  const int ocol = ni * 1024 + ub * 16 + (l & 15);
  const int krow = 1024 + cc * 128 + kkl * 32 + (l >> 4) * 8;
  u16* dst = whfl + ((((long)(d * 64 + ub) * 8 + cc) * 16 + f) << 9) + l * 8;
  const float* src = W + (long)krow * G4_ + ocol;
#pragma unroll
  for (int j = 0; j < 8; ++j) dst[j] = f2h(src[(long)j * G4_]);
}

// ---------------- big x-projection GEMM (128x128 tile, r4-proven) ----------
// xp2 layout [d][t][ub(64)][bh(2)][32][64] fp16, bias folded in.
__global__ __launch_bounds__(256) void gemm_xproj2(const u16* __restrict__ xbf,
                                                   const u16* __restrict__ wT,
                                                   const float* __restrict__ bF,
                                                   const float* __restrict__ bB,
                                                   u16* __restrict__ xp2) {
  __shared__ __align__(16) char smem[64 * 1024];
  const int tid = threadIdx.x, lane = tid & 63, wid = tid >> 6;
  const int wr = wid >> 1, wc = wid & 1;
  const int tm = blockIdx.x * 128, tn = blockIdx.y * 128, d = blockIdx.z;
  const char* Ag = (const char*)xbf + (long)tm * 2048;
  const char* Bg = (const char*)wT + ((long)d * G4_ + tn) * 2048;

  f32x4 acc[4][4];
#pragma unroll
  for (int mi = 0; mi < 4; ++mi)
#pragma unroll
    for (int ni = 0; ni < 4; ++ni)
#pragma unroll
      for (int v = 0; v < 4; ++v) acc[mi][ni][v] = 0.f;

  stage_tile<128>(Ag, 2048, smem, tid);
  stage_tile<128>(Bg, 2048, smem + 32768, tid);
  __syncthreads();
  const int rA = lane & 15, kb = (lane >> 4) * 16;

  for (int cc = 0; cc < 16; ++cc) {
    const int cur = cc & 1;
    char* Ac = smem + cur * 16384;
    char* Bc = smem + 32768 + cur * 16384;
    if (cc + 1 < 16) {
      stage_tile<128>(Ag + (cc + 1) * 128, 2048, smem + (cur ^ 1) * 16384, tid);
      stage_tile<128>(Bg + (cc + 1) * 128, 2048, smem + 32768 + (cur ^ 1) * 16384, tid);
    }
    f16x8 aF[4][2], bFr[4][2];
#pragma unroll
    for (int mi = 0; mi < 4; ++mi)
#pragma unroll
      for (int ks = 0; ks < 2; ++ks)
        aF[mi][ks] = read_frag(Ac, wr * 64 + mi * 16 + rA, kb + ks * 64);
#pragma unroll
    for (int ni = 0; ni < 4; ++ni)
#pragma unroll
      for (int ks = 0; ks < 2; ++ks)
        bFr[ni][ks] = read_frag(Bc, wc * 64 + ni * 16 + rA, kb + ks * 64);
#pragma unroll
    for (int mi = 0; mi < 4; ++mi)
#pragma unroll
      for (int ni = 0; ni < 4; ++ni)
#pragma unroll
        for (int ks = 0; ks < 2; ++ks)
          acc[mi][ni] = MFMA_(aF[mi][ks], bFr[ni][ks], acc[mi][ni]);
    __syncthreads();
  }

  const float* bias = d ? bB : bF;
#pragma unroll
  for (int ni = 0; ni < 4; ++ni) {
    const int p = tn + wc * 64 + ni * 16 + rA;
    const int orig = ((p >> 4) & 3) * 1024 + ((p >> 6) << 4) + (p & 15);
    const float bv = bias[orig];
    const int ub2 = p >> 6, pl = p & 63;
#pragma unroll
    for (int mi = 0; mi < 4; ++mi) {
      const int m0 = tm + wr * 64 + mi * 16 + (lane >> 4) * 4;
#pragma unroll
      for (int v = 0; v < 4; ++v) {
        const int m = m0 + v, b = m >> 9, t = m & 511;
        const int bh = b >> 5, br = b & 31;
        xp2[(((((long)d * T_ + t) * 64 + ub2) * 2 + bh) * 32 + br) * 64 + pl] =
            f2h(acc[mi][ni][v] + bv);
      }
    }
  }
}

// ---------------- per-timestep kernel v11: ring + reg-A + in-register gates --
// grid (128, 2): g -> ub = g>>1, d = g&1; bh = blockIdx.y.
// 256 threads = 4 waves: wm = wid&1 (16 of 32 batch rows), kh = wid>>1 (K half).
// A (h) in registers (16 dwordx4/lane, K-split). W ring: 2 x 32KB slots; phase
// CC stages K=128 for BOTH halves (chunks CC and CC+4). Counted-vmcnt ledger
// identical to r14 (phases 0-2: vmcnt(8); phase 3: vmcnt(0); 8 stages/wave).
// Epilogue: kh1 -> zbuf, ONE barrier, kh0 adds in-register and computes gates
// directly in the MFMA fragment layout (ni = gate, rA = unit, kq*4+v = row).
// c-state in custom float4-per-lane layout; xp as 16 cached ushorts.

__device__ __forceinline__ void stage_Wph(const char* wfl, int cc, char* slot, int tid) {
  const int lane = tid & 63, wid = tid >> 6;
#pragma unroll
  for (int q = 0; q < 8; ++q) {
    const int f = wid * 8 + q;                    // 0..31
    const int chunk = cc + (f >> 4) * 4;          // kh0: cc, kh1: cc+4
    glds16(wfl + (long)(chunk * 16 + (f & 15)) * 1024 + lane * 16,
           slot + f * 1024);
  }
}

template <int CC>
__device__ __forceinline__ void kstep5(char* smem, const char* wfl, int tid,
                                       int kh, const f16x8* ah, f32x4 (&acc)[4]) {
  constexpr int N = (CC < 3) ? 8 : 0;
  asm volatile("s_waitcnt vmcnt(%0)" :: "i"(N) : "memory");
  __builtin_amdgcn_s_barrier();
  asm volatile("" ::: "memory");
  const char* Bslot = smem + (CC & 1) * 32768 + (kh << 14) + ((tid & 63) << 4);
#pragma unroll
  for (int kkl = 0; kkl < 4; ++kkl) {
    const f16x8 a = ah[CC * 4 + kkl];
#pragma unroll
    for (int ni = 0; ni < 4; ++ni)
      acc[ni] = MFMA_(a, *(const f16x8*)(Bslot + ((ni * 4 + kkl) << 10)), acc[ni]);
  }
  asm volatile("s_waitcnt lgkmcnt(0)" ::: "memory");
  __builtin_amdgcn_sched_barrier(0);
  __builtin_amdgcn_s_barrier();
  asm volatile("" ::: "memory");
  if (CC + 2 < 4)
    stage_Wph(wfl, CC + 2, smem + (CC & 1) * 32768, tid);
}

__global__ __launch_bounds__(256) void lstm_step11(
    const u16* __restrict__ whfl, const u16* __restrict__ xp2,
    const u16* __restrict__ h_read, u16* __restrict__ h_write,
    float* __restrict__ cst, float* __restrict__ out, int s) {
  __shared__ __align__(16) char smem[65536 + ZLD * 32 * 4];
  float* zbuf = (float*)(smem + 65536);
  const int tid = threadIdx.x, lane = tid & 63, wid = tid >> 6;
  const int wm = wid & 1, kh = wid >> 1;
  const int g = blockIdx.x, ub = g >> 1, d = g & 1, bh = blockIdx.y;
  const int t = d ? (T_ - 1 - s) : s;
  const int rA = lane & 15, kq = lane >> 4;
  const char* wfl = (const char*)whfl + ((long)(d * 64 + ub) << 17);
  const char* xg = (const char*)xp2 + ((((long)d * T_ + t) * 64 + ub) * 2 + bh) * 4096;
  const int row0 = wm * 16 + kq * 4;  // first of this lane's 4 batch rows

  // ---- issue order (vmcnt ledger): [kh0: c(1) + xp(16)] -> A(16) -> W(16) ----
  f32x4 creg;
  uint32_t xr[4][4];  // [v][gate]
  if (kh == 0) {
    const float* cp = cst + ((((long)(d * 64 + ub) * 2 + bh) * 2 + wm) * 64 + lane) * 4;
    asm volatile("global_load_dwordx4 %0, %1, off" : "=v"(creg) : "v"(cp) : "memory");
#pragma unroll
    for (int v = 0; v < 4; ++v) {
      const char* xt = xg + ((row0 + v) * 64 + rA) * 2;
#define XL(gg)                                                            \
  asm volatile("global_load_ushort %0, %1, off offset:%2"                 \
               : "=v"(xr[v][gg]) : "v"(xt), "n"(gg * 32) : "memory")
      XL(0); XL(1); XL(2); XL(3);
#undef XL
    }
  }
  const char* ah_base =
      (const char*)h_read +
      (((long)d * B_ + bh * 32 + wm * 16 + rA) * 1024 + kh * 512 + kq * 8) * 2;
  f16x8 ah[16];
#define AH(i)                                                             \
  asm volatile("global_load_dwordx4 %0, %1, off offset:%2"                \
               : "=v"(ah[i]) : "v"(ah_base), "n"(i * 64) : "memory")
  AH(0); AH(1); AH(2); AH(3); AH(4); AH(5); AH(6); AH(7);
  AH(8); AH(9); AH(10); AH(11); AH(12); AH(13); AH(14); AH(15);
#undef AH
  stage_Wph(wfl, 0, smem, tid);
  stage_Wph(wfl, 1, smem + 32768, tid);

  f32x4 acc[4];
#pragma unroll
  for (int ni = 0; ni < 4; ++ni)
#pragma unroll
    for (int v = 0; v < 4; ++v) acc[ni][v] = 0.f;

  kstep5<0>(smem, wfl, tid, kh, ah, acc);
  kstep5<1>(smem, wfl, tid, kh, ah, acc);
  kstep5<2>(smem, wfl, tid, kh, ah, acc);
  kstep5<3>(smem, wfl, tid, kh, ah, acc);

  // ---- K-combine: kh1 writes partials; kh0 adds IN-REGISTER after barrier ----
  if (kh == 1) {
#pragma unroll
    for (int ni = 0; ni < 4; ++ni)
#pragma unroll
      for (int v = 0; v < 4; ++v)
        zbuf[(row0 + v) * ZLD + ni * 16 + rA] = acc[ni][v];
  }
  asm volatile("s_waitcnt lgkmcnt(0)\n\ts_barrier" ::: "memory");

  if (kh == 0) {
#pragma unroll
    for (int ni = 0; ni < 4; ++ni)
#pragma unroll
      for (int v = 0; v < 4; ++v)
        acc[ni][v] += zbuf[(row0 + v) * ZLD + ni * 16 + rA];

    // ---- gates in fragment layout: ni = gate (i,f,o,g), v = batch row ----
    const int u_g = ub * 16 + rA;
    float cnew[4], hn[4];
#pragma unroll
    for (int v = 0; v < 4; ++v) {
      const float zi = acc[0][v] + h2f(xr[v][0]);
      const float zf = acc[1][v] + h2f(xr[v][1]);
      const float zo = acc[2][v] + h2f(xr[v][2]);
      const float zg = acc[3][v] + h2f(xr[v][3]);
      const float cn = sigm(zf) * creg[v] + sigm(zi) * tanhf_(zg);
      cnew[v] = cn;
      hn[v] = sigm(zo) * tanhf_(cn);
    }
    float* cp = cst + ((((long)(d * 64 + ub) * 2 + bh) * 2 + wm) * 64 + lane) * 4;
    f32x4 cw;
#pragma unroll
    for (int v = 0; v < 4; ++v) cw[v] = cnew[v];
    *(f32x4*)cp = cw;
#pragma unroll
    for (int v = 0; v < 4; ++v) {
      const int brow = bh * 32 + row0 + v;
      h_write[((long)d * B_ + brow) * 1024 + u_g] = f2h(hn[v]);
      out[((long)brow * T_ + t) * 2048 + d * 1024 + u_g] = hn[v];
    }
  }
}

// ---------------- host launch ----------------

extern "C" void kernel_launch(void* const* d_in, const int* in_sizes, int n_in,
                              void* d_out, int out_size, void* d_ws, size_t ws_size,
                              hipStream_t stream) {
  const float* x = (const float*)d_in[0];
  const float* Wf = (const float*)d_in[1];
  const float* bfp = (const float*)d_in[2];
  const float* Wb = (const float*)d_in[3];
  const float* bbp = (const float*)d_in[4];
  float* out = (float*)d_out;
  char* ws = (char*)d_ws;

  size_t off = 0;
  auto alloc = [&](size_t bytes) {
    char* p = ws + off;
    off = (off + bytes + 255) & ~(size_t)255;
    return p;
  };
  u16* xbf = (u16*)alloc((size_t)M_ * D_ * 2);             // 64 MB
  u16* wxT = (u16*)alloc((size_t)2 * G4_ * 1024 * 2);      // 16 MB
  u16* whfl = (u16*)alloc((size_t)2 * 64 * 128 * 1024);    // 16 MB frag-linear
  u16* hst = (u16*)alloc((size_t)2 * 2 * B_ * U_ * 2);     // 0.5 MB ping-pong h
  float* cst = (float*)alloc((size_t)2 * B_ * U_ * 4);     // 0.5 MB cell state
  u16* xproj = (u16*)alloc((size_t)2 * B_ * T_ * G4_ * 2); // 512 MB

  hipMemsetAsync(hst, 0, (size_t)2 * 2 * B_ * U_ * 2, stream);
  hipMemsetAsync(cst, 0, (size_t)2 * B_ * U_ * 4, stream);

  cast_x_kernel<<<2048, 256, 0, stream>>>(x, xbf);
  pack_wx_kernel<<<2048, 256, 0, stream>>>(Wf, Wb, wxT);
  pack_whfl_kernel<<<4096, 256, 0, stream>>>(Wf, Wb, whfl);

  dim3 gg(M_ / 128, G4_ / 128, 2);
  gemm_xproj2<<<gg, 256, 0, stream>>>(xbf, wxT, bfp, bbp, xproj);

  for (int s = 0; s < T_; ++s) {
    const u16* hr = hst + (size_t)(s & 1) * 2 * B_ * U_;
    u16* hw = hst + (size_t)((s + 1) & 1) * 2 * B_ * U_;
    lstm_step11<<<dim3(128, 2), 256, 0, stream>>>(whfl, xproj, hr, hw, cst, out, s);
  }
}

// Round 16
// 4164.753 us; speedup vs baseline: 1.1154x; 1.1154x over previous
//
#include <hip/hip_runtime.h>
#include <stdint.h>

#define B_ 64
#define T_ 512
#define D_ 1024
#define U_ 1024
#define G4_ 4096
#define M_ (B_ * T_)  // 32768
#define ZLD 65        // zbuf row stride (floats)

typedef unsigned short u16;
typedef float f32x4 __attribute__((ext_vector_type(4)));
typedef _Float16 f16x8 __attribute__((ext_vector_type(8)));
typedef unsigned short u16x4 __attribute__((ext_vector_type(4)));

__device__ __forceinline__ u16 f2h(float f) {
  union { _Float16 h; u16 u; } v; v.h = (_Float16)f; return v.u;
}
__device__ __forceinline__ float h2f(uint32_t u) {
  union { _Float16 h; u16 u; } v; v.u = (u16)u; return (float)v.h;
}
__device__ __forceinline__ float sigm(float x) { return 1.f / (1.f + __expf(-x)); }
__device__ __forceinline__ float tanhf_(float x) {
  x = fminf(12.f, fmaxf(-12.f, x));
  float e = __expf(2.f * x);
  return (e - 1.f) / (e + 1.f);
}

__device__ __forceinline__ void glds16(const void* g, void* l) {
  __builtin_amdgcn_global_load_lds(
      (const __attribute__((address_space(1))) uint32_t*)g,
      (__attribute__((address_space(3))) uint32_t*)l, 16, 0, 0);
}

// row-strided stager for the GEMM (XOR swizzle on global source, rule #21)
template <int R>
__device__ __forceinline__ void stage_tile(const char* gbase, long gs, char* lds, int tid) {
  const int lane = tid & 63, wid = tid >> 6;
#pragma unroll
  for (int j = wid; j < R / 8; j += 4) {
    const int row = j * 8 + (lane >> 3);
    const int lg = ((lane & 7) * 16) ^ ((row & 7) << 4);
    glds16(gbase + (long)row * gs + lg, lds + j * 1024);
  }
}

__device__ __forceinline__ f16x8 read_frag(const char* lds, int row, int kbyte) {
  const int ph = row * 128 + (kbyte ^ ((row & 7) << 4));
  return *(const f16x8*)(lds + ph);
}

#define MFMA_(a, b, c) __builtin_amdgcn_mfma_f32_16x16x32_f16(a, b, c, 0, 0, 0)

// ---------------- prep kernels ----------------

__global__ __launch_bounds__(256) void cast_x_kernel(const float* __restrict__ x,
                                                     u16* __restrict__ xb) {
  const long n = (long)M_ * D_ / 4;
  for (long i = (long)blockIdx.x * blockDim.x + threadIdx.x; i < n;
       i += (long)gridDim.x * blockDim.x) {
    f32x4 v = ((const f32x4*)x)[i];
    u16x4 r;
#pragma unroll
    for (int j = 0; j < 4; ++j) r[j] = f2h(v[j]);
    ((u16x4*)xb)[i] = r;
  }
}

// x-part weights, k-major 16-unit packing (GEMM B operand).
// p = ub*64 + g*16 + ui  <->  orig col = g*1024 + ub*16 + ui.
__global__ __launch_bounds__(256) void pack_wx_kernel(const float* __restrict__ Wf,
                                                      const float* __restrict__ Wb,
                                                      u16* __restrict__ wxT) {
  const int idx = blockIdx.x * 256 + threadIdx.x;  // 2*64*4096 = 2^19
  const int p = idx & 4095;
  const int kc = (idx >> 12) & 63;
  const int d = (idx >> 18) & 1;
  const float* W = d ? Wb : Wf;
  const int orig = ((p >> 4) & 3) * 1024 + ((p >> 6) << 4) + (p & 15);
  u16* dst = wxT + ((long)d * G4_ + p) * 1024 + kc * 16;
  const float* src = W + (long)(kc * 16) * G4_ + orig;
#pragma unroll
  for (int j = 0; j < 16; ++j) dst[j] = f2h(src[(long)j * G4_]);
}

// h-part weights, FRAGMENT-LINEAR: per (d, ub<64): 8 chunks x 16 frags x 1KB.
// frag f = ni*4 + kkl ; lane l elem j: col = ni*1024 + ub*16 + (l&15) [gate=ni]
//   k row = 1024 + cc*128 + kkl*32 + (l>>4)*8 + j
__global__ __launch_bounds__(256) void pack_whfl_kernel(const float* __restrict__ Wf,
                                                        const float* __restrict__ Wb,
                                                        u16* __restrict__ whfl) {
  const int idx = blockIdx.x * 256 + threadIdx.x;  // 2^20
  const int l = idx & 63;
  const int f = (idx >> 6) & 15;
  const int cc = (idx >> 10) & 7;
  const int ub = (idx >> 13) & 63;
  const int d = (idx >> 19) & 1;
  const float* W = d ? Wb : Wf;
  const int ni = f >> 2, kkl = f & 3;
  const int ocol = ni * 1024 + ub * 16 + (l & 15);
  const int krow = 1024 + cc * 128 + kkl * 32 + (l >> 4) * 8;
  u16* dst = whfl + ((((long)(d * 64 + ub) * 8 + cc) * 16 + f) << 9) + l * 8;
  const float* src = W + (long)krow * G4_ + ocol;
#pragma unroll
  for (int j = 0; j < 8; ++j) dst[j] = f2h(src[(long)j * G4_]);
}

// ---------------- big x-projection GEMM (128x128 tile, r4-proven) ----------
// xp2 layout [d][t][ub(64)][b(64)][pl(64)] fp16, bias folded in.
__global__ __launch_bounds__(256) void gemm_xproj2(const u16* __restrict__ xbf,
                                                   const u16* __restrict__ wT,
                                                   const float* __restrict__ bF,
                                                   const float* __restrict__ bB,
                                                   u16* __restrict__ xp2) {
  __shared__ __align__(16) char smem[64 * 1024];
  const int tid = threadIdx.x, lane = tid & 63, wid = tid >> 6;
  const int wr = wid >> 1, wc = wid & 1;
  const int tm = blockIdx.x * 128, tn = blockIdx.y * 128, d = blockIdx.z;
  const char* Ag = (const char*)xbf + (long)tm * 2048;
  const char* Bg = (const char*)wT + ((long)d * G4_ + tn) * 2048;

  f32x4 acc[4][4];
#pragma unroll
  for (int mi = 0; mi < 4; ++mi)
#pragma unroll
    for (int ni = 0; ni < 4; ++ni)
#pragma unroll
      for (int v = 0; v < 4; ++v) acc[mi][ni][v] = 0.f;

  stage_tile<128>(Ag, 2048, smem, tid);
  stage_tile<128>(Bg, 2048, smem + 32768, tid);
  __syncthreads();
  const int rA = lane & 15, kb = (lane >> 4) * 16;

  for (int cc = 0; cc < 16; ++cc) {
    const int cur = cc & 1;
    char* Ac = smem + cur * 16384;
    char* Bc = smem + 32768 + cur * 16384;
    if (cc + 1 < 16) {
      stage_tile<128>(Ag + (cc + 1) * 128, 2048, smem + (cur ^ 1) * 16384, tid);
      stage_tile<128>(Bg + (cc + 1) * 128, 2048, smem + 32768 + (cur ^ 1) * 16384, tid);
    }
    f16x8 aF[4][2], bFr[4][2];
#pragma unroll
    for (int mi = 0; mi < 4; ++mi)
#pragma unroll
      for (int ks = 0; ks < 2; ++ks)
        aF[mi][ks] = read_frag(Ac, wr * 64 + mi * 16 + rA, kb + ks * 64);
#pragma unroll
    for (int ni = 0; ni < 4; ++ni)
#pragma unroll
      for (int ks = 0; ks < 2; ++ks)
        bFr[ni][ks] = read_frag(Bc, wc * 64 + ni * 16 + rA, kb + ks * 64);
#pragma unroll
    for (int mi = 0; mi < 4; ++mi)
#pragma unroll
      for (int ni = 0; ni < 4; ++ni)
#pragma unroll
        for (int ks = 0; ks < 2; ++ks)
          acc[mi][ni] = MFMA_(aF[mi][ks], bFr[ni][ks], acc[mi][ni]);
    __syncthreads();
  }

  const float* bias = d ? bB : bF;
#pragma unroll
  for (int ni = 0; ni < 4; ++ni) {
    const int p = tn + wc * 64 + ni * 16 + rA;
    const int orig = ((p >> 4) & 3) * 1024 + ((p >> 6) << 4) + (p & 15);
    const float bv = bias[orig];
    const int ub2 = p >> 6, pl = p & 63;
#pragma unroll
    for (int mi = 0; mi < 4; ++mi) {
      const int m0 = tm + wr * 64 + mi * 16 + (lane >> 4) * 4;
#pragma unroll
      for (int v = 0; v < 4; ++v) {
        const int m = m0 + v, b = m >> 9, t = m & 511;
        xp2[((((long)d * T_ + t) * 64 + ub2) * 64 + b) * 64 + pl] =
            f2h(acc[mi][ni][v] + bv);
      }
    }
  }
}

// ---------------- per-timestep kernel v12: r12 datapath at 2 blocks/CU ------
// grid (128, 4): g -> ub = g>>1, d = g&1; bh = blockIdx.y (16 batch rows).
// 256 threads = 4 waves; wave wg = gate (col group wg*16..+15), FULL K each.
// LDS: A(h) 32KB | ring 2 x 16KB (8 phases of K=128, depth-1 prefetch) | zbuf
// = ~68KB -> 2 blocks/CU. Counted-vmcnt ledger (issue: c1,xp4,A8,B0:4,B1:4):
// phases 0-6 vmcnt(4), phase 7 vmcnt(0). No K-combine (full-K waves): one
// epilogue barrier, one unit/thread gates.

__device__ __forceinline__ void stage_hA16(const char* g, char* lds, int tid) {
  const int lane = tid & 63, wid = tid >> 6;
#pragma unroll
  for (int q = 0; q < 8; ++q) {
    const int idx = wid * 8 + q;            // 32 x 1KB
    const int row = idx * 8 + (lane >> 3);  // 128B-row in [0,256)
    const int off = ((lane & 7) * 16) ^ (((row >> 4) & 7) << 4);  // swz by h-row
    glds16(g + (long)row * 128 + off, lds + idx * 1024);
  }
}

// K=128 chunk stage: 16 x 1KB contiguous frags, 4 glds16/wave
__device__ __forceinline__ void stage_Bc(const char* wfl, int cc, char* slot, int tid) {
  const int lane = tid & 63, wid = tid >> 6;
#pragma unroll
  for (int q = 0; q < 4; ++q) {
    const int f = wid * 4 + q;
    glds16(wfl + (long)cc * 16384 + f * 1024 + lane * 16, slot + f * 1024);
  }
}

template <int CC>
__device__ __forceinline__ void kstepv(char* smem, const char* wfl, int tid,
                                       int wg, int rA, int kq, f32x4& acc) {
  constexpr int N = (CC < 7) ? 4 : 0;
  asm volatile("s_waitcnt vmcnt(%0)" :: "i"(N) : "memory");
  __builtin_amdgcn_s_barrier();
  asm volatile("" ::: "memory");
  const char* A = smem;
  const char* Bslot = smem + 32768 + (CC & 1) * 16384;
  const int lane16 = (tid & 63) << 4;
  f16x8 aF[4], bF[4];
#pragma unroll
  for (int ks = 0; ks < 4; ++ks) {
    const int kbyte = CC * 256 + ks * 64 + kq * 16;
    aF[ks] = *(const f16x8*)(A + rA * 2048 + (kbyte ^ ((rA & 7) << 4)));
  }
#pragma unroll
  for (int ks = 0; ks < 4; ++ks)
    bF[ks] = *(const f16x8*)(Bslot + (wg * 4 + ks) * 1024 + lane16);
#pragma unroll
  for (int ks = 0; ks < 4; ++ks)
    acc = MFMA_(aF[ks], bF[ks], acc);
  asm volatile("s_waitcnt lgkmcnt(0)" ::: "memory");
  __builtin_amdgcn_sched_barrier(0);
  __builtin_amdgcn_s_barrier();
  asm volatile("" ::: "memory");
  if (CC + 2 < 8)
    stage_Bc(wfl, CC + 2, smem + 32768 + (CC & 1) * 16384, tid);
}

__global__ __launch_bounds__(256, 2) void lstm_step12(
    const u16* __restrict__ whfl, const u16* __restrict__ xp2,
    const u16* __restrict__ h_read, u16* __restrict__ h_write,
    float* __restrict__ cst, float* __restrict__ out, int s) {
  __shared__ __align__(16) char smem[32768 + 32768 + ZLD * 16 * 4];
  float* zbuf = (float*)(smem + 65536);
  const int tid = threadIdx.x, lane = tid & 63, wg = tid >> 6;
  const int g = blockIdx.x, ub = g >> 1, d = g & 1, bh = blockIdx.y;
  const int t = d ? (T_ - 1 - s) : s;
  const int rA = lane & 15, kq = lane >> 4;
  const char* wfl = (const char*)whfl + ((long)(d * 64 + ub) << 17);
  const char* hA = (const char*)h_read + ((long)d * B_ + bh * 16) * 2048;

  // gate-thread identity: one unit per thread
  const int row_g = tid >> 4, ui_g = tid & 15;
  const int bglob = bh * 16 + row_g;
  const int u_g = ub * 16 + ui_g;

  // ---- issue order (vmcnt ledger): c(1) -> xp(4) -> A(8) -> B0(4), B1(4) ----
  float creg;
  {
    const float* cp = cst + ((long)d * B_ + bglob) * 1024 + u_g;
    asm volatile("global_load_dword %0, %1, off" : "=v"(creg) : "v"(cp) : "memory");
  }
  uint32_t xr[4];
  {
    const char* xt = (const char*)xp2 +
        (((((long)d * T_ + t) * 64 + ub) * 64 + bglob) * 64 + ui_g) * 2;
#define XL(gg)                                                            \
  asm volatile("global_load_ushort %0, %1, off offset:%2"                 \
               : "=v"(xr[gg]) : "v"(xt), "n"(gg * 32) : "memory")
    XL(0); XL(1); XL(2); XL(3);
#undef XL
  }
  stage_hA16(hA, smem, tid);
  stage_Bc(wfl, 0, smem + 32768, tid);
  stage_Bc(wfl, 1, smem + 32768 + 16384, tid);

  f32x4 acc;
#pragma unroll
  for (int v = 0; v < 4; ++v) acc[v] = 0.f;

  kstepv<0>(smem, wfl, tid, wg, rA, kq, acc);
  kstepv<1>(smem, wfl, tid, wg, rA, kq, acc);
  kstepv<2>(smem, wfl, tid, wg, rA, kq, acc);
  kstepv<3>(smem, wfl, tid, wg, rA, kq, acc);
  kstepv<4>(smem, wfl, tid, wg, rA, kq, acc);
  kstepv<5>(smem, wfl, tid, wg, rA, kq, acc);
  kstepv<6>(smem, wfl, tid, wg, rA, kq, acc);
  kstepv<7>(smem, wfl, tid, wg, rA, kq, acc);

  // ---- z -> zbuf (C layout: col = rA (unit), row = kq*4+v (batch)) ----
#pragma unroll
  for (int v = 0; v < 4; ++v)
    zbuf[(kq * 4 + v) * ZLD + wg * 16 + rA] = acc[v];
  __syncthreads();

  // ---- gates: one unit of one batch row per thread ----
  {
    const float* zb = zbuf + row_g * ZLD + ui_g;
    const float zi = zb[0]  + h2f(xr[0]);
    const float zf = zb[16] + h2f(xr[1]);
    const float zo = zb[32] + h2f(xr[2]);
    const float zg = zb[48] + h2f(xr[3]);
    const float cn = sigm(zf) * creg + sigm(zi) * tanhf_(zg);
    const float hn = sigm(zo) * tanhf_(cn);
    cst[((long)d * B_ + bglob) * 1024 + u_g] = cn;
    h_write[((long)d * B_ + bglob) * 1024 + u_g] = f2h(hn);
    out[((long)bglob * T_ + t) * 2048 + d * 1024 + u_g] = hn;
  }
}

// ---------------- host launch ----------------

extern "C" void kernel_launch(void* const* d_in, const int* in_sizes, int n_in,
                              void* d_out, int out_size, void* d_ws, size_t ws_size,
                              hipStream_t stream) {
  const float* x = (const float*)d_in[0];
  const float* Wf = (const float*)d_in[1];
  const float* bfp = (const float*)d_in[2];
  const float* Wb = (const float*)d_in[3];
  const float* bbp = (const float*)d_in[4];
  float* out = (float*)d_out;
  char* ws = (char*)d_ws;

  size_t off = 0;
  auto alloc = [&](size_t bytes) {
    char* p = ws + off;
    off = (off + bytes + 255) & ~(size_t)255;
    return p;
  };
  u16* xbf = (u16*)alloc((size_t)M_ * D_ * 2);             // 64 MB
  u16* wxT = (u16*)alloc((size_t)2 * G4_ * 1024 * 2);      // 16 MB
  u16* whfl = (u16*)alloc((size_t)2 * 64 * 128 * 1024);    // 16 MB frag-linear
  u16* hst = (u16*)alloc((size_t)2 * 2 * B_ * U_ * 2);     // 0.5 MB ping-pong h
  float* cst = (float*)alloc((size_t)2 * B_ * U_ * 4);     // 0.5 MB cell state
  u16* xproj = (u16*)alloc((size_t)2 * B_ * T_ * G4_ * 2); // 512 MB

  hipMemsetAsync(hst, 0, (size_t)2 * 2 * B_ * U_ * 2, stream);
  hipMemsetAsync(cst, 0, (size_t)2 * B_ * U_ * 4, stream);

  cast_x_kernel<<<2048, 256, 0, stream>>>(x, xbf);
  pack_wx_kernel<<<2048, 256, 0, stream>>>(Wf, Wb, wxT);
  pack_whfl_kernel<<<4096, 256, 0, stream>>>(Wf, Wb, whfl);

  dim3 gg(M_ / 128, G4_ / 128, 2);
  gemm_xproj2<<<gg, 256, 0, stream>>>(xbf, wxT, bfp, bbp, xproj);

  for (int s = 0; s < T_; ++s) {
    const u16* hr = hst + (size_t)(s & 1) * 2 * B_ * U_;
    u16* hw = hst + (size_t)((s + 1) & 1) * 2 * B_ * U_;
    lstm_step12<<<dim3(128, 4), 256, 0, stream>>>(whfl, xproj, hr, hw, cst, out, s);
  }
}

// Round 17
// 3992.924 us; speedup vs baseline: 1.1634x; 1.0430x over previous
//
#include <hip/hip_runtime.h>
#include <stdint.h>

#define B_ 64
#define T_ 512
#define D_ 1024
#define U_ 1024
#define G4_ 4096
#define M_ (B_ * T_)  // 32768
#define ZLD 65        // zbuf row stride (floats)

typedef unsigned short u16;
typedef float f32x4 __attribute__((ext_vector_type(4)));
typedef _Float16 f16x8 __attribute__((ext_vector_type(8)));
typedef unsigned short u16x4 __attribute__((ext_vector_type(4)));

__device__ __forceinline__ u16 f2h(float f) {
  union { _Float16 h; u16 u; } v; v.h = (_Float16)f; return v.u;
}
__device__ __forceinline__ float h2f(uint32_t u) {
  union { _Float16 h; u16 u; } v; v.u = (u16)u; return (float)v.h;
}
__device__ __forceinline__ float sigm(float x) { return 1.f / (1.f + __expf(-x)); }
__device__ __forceinline__ float tanhf_(float x) {
  x = fminf(12.f, fmaxf(-12.f, x));
  float e = __expf(2.f * x);
  return (e - 1.f) / (e + 1.f);
}

__device__ __forceinline__ void glds16(const void* g, void* l) {
  __builtin_amdgcn_global_load_lds(
      (const __attribute__((address_space(1))) uint32_t*)g,
      (__attribute__((address_space(3))) uint32_t*)l, 16, 0, 0);
}

// row-strided stager (XOR swizzle on global source, rule #21); LDS linear.
template <int R>
__device__ __forceinline__ void stage_tile(const char* gbase, long gs, char* lds, int tid) {
  const int lane = tid & 63, wid = tid >> 6;
#pragma unroll
  for (int j = wid; j < R / 8; j += 4) {
    const int row = j * 8 + (lane >> 3);
    const int lg = ((lane & 7) * 16) ^ ((row & 7) << 4);
    glds16(gbase + (long)row * gs + lg, lds + j * 1024);
  }
}

__device__ __forceinline__ f16x8 read_frag(const char* lds, int row, int kbyte) {
  const int ph = row * 128 + (kbyte ^ ((row & 7) << 4));
  return *(const f16x8*)(lds + ph);
}

#define MFMA_(a, b, c) __builtin_amdgcn_mfma_f32_16x16x32_f16(a, b, c, 0, 0, 0)

// ---------------- prep kernels ----------------

__global__ __launch_bounds__(256) void cast_x_kernel(const float* __restrict__ x,
                                                     u16* __restrict__ xb) {
  const long n = (long)M_ * D_ / 4;
  for (long i = (long)blockIdx.x * blockDim.x + threadIdx.x; i < n;
       i += (long)gridDim.x * blockDim.x) {
    f32x4 v = ((const f32x4*)x)[i];
    u16x4 r;
#pragma unroll
    for (int j = 0; j < 4; ++j) r[j] = f2h(v[j]);
    ((u16x4*)xb)[i] = r;
  }
}

// x-part weights, k-major 16-unit packing (GEMM B operand).
// p = ub*64 + g*16 + ui  <->  orig col = g*1024 + ub*16 + ui.
__global__ __launch_bounds__(256) void pack_wx_kernel(const float* __restrict__ Wf,
                                                      const float* __restrict__ Wb,
                                                      u16* __restrict__ wxT) {
  const int idx = blockIdx.x * 256 + threadIdx.x;  // 2*64*4096 = 2^19
  const int p = idx & 4095;
  const int kc = (idx >> 12) & 63;
  const int d = (idx >> 18) & 1;
  const float* W = d ? Wb : Wf;
  const int orig = ((p >> 4) & 3) * 1024 + ((p >> 6) << 4) + (p & 15);
  u16* dst = wxT + ((long)d * G4_ + p) * 1024 + kc * 16;
  const float* src = W + (long)(kc * 16) * G4_ + orig;
#pragma unroll
  for (int j = 0; j < 16; ++j) dst[j] = f2h(src[(long)j * G4_]);
}

// h-part weights, FRAGMENT-LINEAR: per (d, ub<64): 8 chunks x 16 frags x 1KB.
// frag f = ni*4 + kkl ; lane l elem j: col = ni*1024 + ub*16 + (l&15) [gate=ni]
//   k row = 1024 + cc*128 + kkl*32 + (l>>4)*8 + j
__global__ __launch_bounds__(256) void pack_whfl_kernel(const float* __restrict__ Wf,
                                                        const float* __restrict__ Wb,
                                                        u16* __restrict__ whfl) {
  const int idx = blockIdx.x * 256 + threadIdx.x;  // 2^20
  const int l = idx & 63;
  const int f = (idx >> 6) & 15;
  const int cc = (idx >> 10) & 7;
  const int ub = (idx >> 13) & 63;
  const int d = (idx >> 19) & 1;
  const float* W = d ? Wb : Wf;
  const int ni = f >> 2, kkl = f & 3;
  const int ocol = ni * 1024 + ub * 16 + (l & 15);
  const int krow = 1024 + cc * 128 + kkl * 32 + (l >> 4) * 8;
  u16* dst = whfl + ((((long)(d * 64 + ub) * 8 + cc) * 16 + f) << 9) + l * 8;
  const float* src = W + (long)krow * G4_ + ocol;
#pragma unroll
  for (int j = 0; j < 8; ++j) dst[j] = f2h(src[(long)j * G4_]);
}

// ---------------- big x-projection GEMM: counted-vmcnt ring (T3/T4) --------
// 128x128 tile, 4 waves; A/B double-buffered 16KB slots; loads stay in
// flight across barriers (vmcnt(8) per cc, never 0 mid-loop).
// xp2 layout [d][t][ub(64)][bh(2)][32][64] fp16, bias folded in.

template <int CC>
__device__ __forceinline__ void gstep(char* smem, const char* Ag, const char* Bg,
                                      int tid, int wr, int wc, int rA, int kb,
                                      f32x4 (&acc)[4][4]) {
  constexpr int N = (CC < 15) ? 8 : 0;
  asm volatile("s_waitcnt vmcnt(%0)" :: "i"(N) : "memory");
  __builtin_amdgcn_s_barrier();
  asm volatile("" ::: "memory");
  const char* Ac = smem + (CC & 1) * 16384;
  const char* Bc = smem + 32768 + (CC & 1) * 16384;
  f16x8 aF[4][2], bFr[4][2];
#pragma unroll
  for (int mi = 0; mi < 4; ++mi)
#pragma unroll
    for (int ks = 0; ks < 2; ++ks)
      aF[mi][ks] = read_frag(Ac, wr * 64 + mi * 16 + rA, kb + ks * 64);
#pragma unroll
  for (int ni = 0; ni < 4; ++ni)
#pragma unroll
    for (int ks = 0; ks < 2; ++ks)
      bFr[ni][ks] = read_frag(Bc, wc * 64 + ni * 16 + rA, kb + ks * 64);
#pragma unroll
  for (int mi = 0; mi < 4; ++mi)
#pragma unroll
    for (int ni = 0; ni < 4; ++ni)
#pragma unroll
      for (int ks = 0; ks < 2; ++ks)
        acc[mi][ni] = MFMA_(aF[mi][ks], bFr[ni][ks], acc[mi][ni]);
  asm volatile("s_waitcnt lgkmcnt(0)" ::: "memory");
  __builtin_amdgcn_sched_barrier(0);
  __builtin_amdgcn_s_barrier();
  asm volatile("" ::: "memory");
  if (CC + 2 < 16) {
    stage_tile<128>(Ag + (CC + 2) * 128, 2048, smem + (CC & 1) * 16384, tid);
    stage_tile<128>(Bg + (CC + 2) * 128, 2048, smem + 32768 + (CC & 1) * 16384, tid);
  }
}

__global__ __launch_bounds__(256) void gemm_xproj3(const u16* __restrict__ xbf,
                                                   const u16* __restrict__ wT,
                                                   const float* __restrict__ bF,
                                                   const float* __restrict__ bB,
                                                   u16* __restrict__ xp2) {
  __shared__ __align__(16) char smem[64 * 1024];
  const int tid = threadIdx.x, lane = tid & 63, wid = tid >> 6;
  const int wr = wid >> 1, wc = wid & 1;
  const int tm = blockIdx.x * 128, tn = blockIdx.y * 128, d = blockIdx.z;
  const char* Ag = (const char*)xbf + (long)tm * 2048;
  const char* Bg = (const char*)wT + ((long)d * G4_ + tn) * 2048;

  f32x4 acc[4][4];
#pragma unroll
  for (int mi = 0; mi < 4; ++mi)
#pragma unroll
    for (int ni = 0; ni < 4; ++ni)
#pragma unroll
      for (int v = 0; v < 4; ++v) acc[mi][ni][v] = 0.f;

  // prologue: stage chunks 0 and 1 (16 glds16/wave outstanding)
  stage_tile<128>(Ag, 2048, smem, tid);
  stage_tile<128>(Bg, 2048, smem + 32768, tid);
  stage_tile<128>(Ag + 128, 2048, smem + 16384, tid);
  stage_tile<128>(Bg + 128, 2048, smem + 32768 + 16384, tid);

  const int rA = lane & 15, kb = (lane >> 4) * 16;

  gstep<0>(smem, Ag, Bg, tid, wr, wc, rA, kb, acc);
  gstep<1>(smem, Ag, Bg, tid, wr, wc, rA, kb, acc);
  gstep<2>(smem, Ag, Bg, tid, wr, wc, rA, kb, acc);
  gstep<3>(smem, Ag, Bg, tid, wr, wc, rA, kb, acc);
  gstep<4>(smem, Ag, Bg, tid, wr, wc, rA, kb, acc);
  gstep<5>(smem, Ag, Bg, tid, wr, wc, rA, kb, acc);
  gstep<6>(smem, Ag, Bg, tid, wr, wc, rA, kb, acc);
  gstep<7>(smem, Ag, Bg, tid, wr, wc, rA, kb, acc);
  gstep<8>(smem, Ag, Bg, tid, wr, wc, rA, kb, acc);
  gstep<9>(smem, Ag, Bg, tid, wr, wc, rA, kb, acc);
  gstep<10>(smem, Ag, Bg, tid, wr, wc, rA, kb, acc);
  gstep<11>(smem, Ag, Bg, tid, wr, wc, rA, kb, acc);
  gstep<12>(smem, Ag, Bg, tid, wr, wc, rA, kb, acc);
  gstep<13>(smem, Ag, Bg, tid, wr, wc, rA, kb, acc);
  gstep<14>(smem, Ag, Bg, tid, wr, wc, rA, kb, acc);
  gstep<15>(smem, Ag, Bg, tid, wr, wc, rA, kb, acc);

  const float* bias = d ? bB : bF;
#pragma unroll
  for (int ni = 0; ni < 4; ++ni) {
    const int p = tn + wc * 64 + ni * 16 + rA;
    const int orig = ((p >> 4) & 3) * 1024 + ((p >> 6) << 4) + (p & 15);
    const float bv = bias[orig];
    const int ub2 = p >> 6, pl = p & 63;
#pragma unroll
    for (int mi = 0; mi < 4; ++mi) {
      const int m0 = tm + wr * 64 + mi * 16 + (lane >> 4) * 4;
#pragma unroll
      for (int v = 0; v < 4; ++v) {
        const int m = m0 + v, b = m >> 9, t = m & 511;
        const int bh = b >> 5, br = b & 31;
        xp2[(((((long)d * T_ + t) * 64 + ub2) * 2 + bh) * 32 + br) * 64 + pl] =
            f2h(acc[mi][ni][v] + bv);
      }
    }
  }
}

// ---------------- per-timestep kernel (r12-verbatim champion) --------------
// grid (128, 2): g = blockIdx.x -> ub = g>>1, d = g&1; bh = blockIdx.y.
// Block: 32 batch x 64 packed cols (16 units), K=1024.
// LDS: A(h) 64KB resident; Wh ring 4 x 16KB (8 chunks of K=128, frag-linear);
// zbuf. Counted-vmcnt pipeline, raw barriers.

__device__ __forceinline__ void stage_hA(const char* g, char* lds, int tid) {
  const int lane = tid & 63, wid = tid >> 6;
#pragma unroll
  for (int q = 0; q < 16; ++q) {
    const int idx = wid + q * 4;            // 64 x 1KB
    const int row = idx * 8 + (lane >> 3);  // 128B-row in [0,512)
    const int off = ((lane & 7) * 16) ^ (((row >> 4) & 7) << 4);  // swz by h-row
    glds16(g + (long)row * 128 + off, lds + idx * 1024);
  }
}

// fragment-linear chunk stage: 16 x 1KB contiguous, 4 glds16/wave
__device__ __forceinline__ void stage_Bc(const char* wfl, int cc, char* slot, int tid) {
  const int lane = tid & 63, wid = tid >> 6;
#pragma unroll
  for (int q = 0; q < 4; ++q) {
    const int f = wid * 4 + q;
    glds16(wfl + (long)cc * 16384 + f * 1024 + lane * 16, slot + f * 1024);
  }
}

template <int CC>
__device__ __forceinline__ void kstep(char* smem, const char* wfl, int tid,
                                      int wr, int wc, int rA, int kq,
                                      f32x4 (&acc)[2]) {
  constexpr int REM = 7 - CC;
  constexpr int N = 4 * (REM < 3 ? REM : 3);
  asm volatile("s_waitcnt vmcnt(%0)" :: "i"(N) : "memory");
  __builtin_amdgcn_s_barrier();
  asm volatile("" ::: "memory");
  const char* A = smem;
  const char* Bslot = smem + 65536 + (CC & 3) * 16384;
  const int lane16 = (tid & 63) << 4;
  f16x8 aF[4], bF[2][4];
  const int br = wr * 16 + rA;
#pragma unroll
  for (int ks = 0; ks < 4; ++ks) {
    const int kbyte = CC * 256 + ks * 64 + kq * 16;
    aF[ks] = *(const f16x8*)(A + br * 2048 + (kbyte ^ ((br & 7) << 4)));
  }
#pragma unroll
  for (int ni = 0; ni < 2; ++ni)
#pragma unroll
    for (int ks = 0; ks < 4; ++ks)
      bF[ni][ks] = *(const f16x8*)(Bslot + ((wc * 2 + ni) * 4 + ks) * 1024 + lane16);
#pragma unroll
  for (int ni = 0; ni < 2; ++ni)
#pragma unroll
    for (int ks = 0; ks < 4; ++ks)
      acc[ni] = MFMA_(aF[ks], bF[ni][ks], acc[ni]);
  asm volatile("s_waitcnt lgkmcnt(0)" ::: "memory");
  __builtin_amdgcn_sched_barrier(0);
  __builtin_amdgcn_s_barrier();
  asm volatile("" ::: "memory");
  if (CC + 4 < 8)
    stage_Bc(wfl, CC + 4, smem + 65536 + ((CC + 4) & 3) * 16384, tid);
}

__global__ __launch_bounds__(256) void lstm_step8(
    const u16* __restrict__ whfl, const u16* __restrict__ xp2,
    const u16* __restrict__ h_read, u16* __restrict__ h_write,
    float* __restrict__ cst, float* __restrict__ out, int s) {
  __shared__ __align__(16) char smem[131072 + ZLD * 32 * 4];
  float* zbuf = (float*)(smem + 131072);
  const int tid = threadIdx.x, lane = tid & 63, wid = tid >> 6;
  const int wr = wid >> 1, wc = wid & 1;
  const int g = blockIdx.x, ub = g >> 1, d = g & 1, bh = blockIdx.y;
  const int t = d ? (T_ - 1 - s) : s;
  const char* hA = (const char*)h_read + ((long)d * B_ + bh * 32) * 2048;
  const char* wfl = (const char*)whfl + ((long)(d * 64 + ub) << 17);
  const char* xg = (const char*)xp2 + ((((long)d * T_ + t) * 64 + ub) * 2 + bh) * 4096;
  const int rA = lane & 15, kq = lane >> 4;

  // gate-thread identity: o = 2*tid -> bl = tid>>3, ui = (tid&7)*2
  const int bl_g = tid >> 3, ui_g = (tid & 7) * 2;
  const int u_g = ub * 16 + ui_g;
  const int bglob = bh * 32 + bl_g;

  // ---- issue order (vmcnt counting): xp(4) -> A(16) -> B0..B3(16) ----
  uint32_t xr[4];
  const char* xt = xg + (bl_g * 64 + ui_g) * 2;
#define XL(gg)                                                          \
  asm volatile("global_load_dword %0, %1, off offset:%2"               \
               : "=v"(xr[gg]) : "v"(xt), "n"(gg * 32) : "memory")
  XL(0); XL(1); XL(2); XL(3);
#undef XL
  stage_hA(hA, smem, tid);
#pragma unroll
  for (int c0 = 0; c0 < 4; ++c0)
    stage_Bc(wfl, c0, smem + 65536 + c0 * 16384, tid);

  // c-state prefetch (cached float2; compiler-managed wait)
  const float2 creg = *(const float2*)(cst + ((long)d * B_ + bglob) * 1024 + u_g);

  f32x4 acc[2];
#pragma unroll
  for (int ni = 0; ni < 2; ++ni)
#pragma unroll
    for (int v = 0; v < 4; ++v) acc[ni][v] = 0.f;

  kstep<0>(smem, wfl, tid, wr, wc, rA, kq, acc);
  kstep<1>(smem, wfl, tid, wr, wc, rA, kq, acc);
  kstep<2>(smem, wfl, tid, wr, wc, rA, kq, acc);
  kstep<3>(smem, wfl, tid, wr, wc, rA, kq, acc);
  kstep<4>(smem, wfl, tid, wr, wc, rA, kq, acc);
  kstep<5>(smem, wfl, tid, wr, wc, rA, kq, acc);
  kstep<6>(smem, wfl, tid, wr, wc, rA, kq, acc);
  kstep<7>(smem, wfl, tid, wr, wc, rA, kq, acc);

  // ---- z -> zbuf exchange ----
#pragma unroll
  for (int ni = 0; ni < 2; ++ni)
#pragma unroll
    for (int v = 0; v < 4; ++v) {
      const int row = wr * 16 + kq * 4 + v;
      const int col = (wc * 2 + ni) * 16 + rA;  // = gate*16 + unit
      zbuf[row * ZLD + col] = acc[ni][v];
    }
  __syncthreads();

  // ---- gates: 2 adjacent units of one batch row per thread ----
  {
    const float* zb = zbuf + bl_g * ZLD + ui_g;
    const float zi0 = zb[0]  + h2f(xr[0] & 0xffff);
    const float zi1 = zb[1]  + h2f(xr[0] >> 16);
    const float zf0 = zb[16] + h2f(xr[1] & 0xffff);
    const float zf1 = zb[17] + h2f(xr[1] >> 16);
    const float zo0 = zb[32] + h2f(xr[2] & 0xffff);
    const float zo1 = zb[33] + h2f(xr[2] >> 16);
    const float zg0 = zb[48] + h2f(xr[3] & 0xffff);
    const float zg1 = zb[49] + h2f(xr[3] >> 16);
    const float cn0 = sigm(zf0) * creg.x + sigm(zi0) * tanhf_(zg0);
    const float cn1 = sigm(zf1) * creg.y + sigm(zi1) * tanhf_(zg1);
    const float hn0 = sigm(zo0) * tanhf_(cn0);
    const float hn1 = sigm(zo1) * tanhf_(cn1);

    float2 cw; cw.x = cn0; cw.y = cn1;
    *(float2*)(cst + ((long)d * B_ + bglob) * 1024 + u_g) = cw;
    const uint32_t hv = (uint32_t)f2h(hn0) | ((uint32_t)f2h(hn1) << 16);
    *(uint32_t*)(h_write + ((long)d * B_ + bglob) * 1024 + u_g) = hv;
    float2 o2; o2.x = hn0; o2.y = hn1;
    *(float2*)(out + ((long)bglob * T_ + t) * 2048 + d * 1024 + u_g) = o2;
  }
}

// ---------------- host launch ----------------

extern "C" void kernel_launch(void* const* d_in, const int* in_sizes, int n_in,
                              void* d_out, int out_size, void* d_ws, size_t ws_size,
                              hipStream_t stream) {
  const float* x = (const float*)d_in[0];
  const float* Wf = (const float*)d_in[1];
  const float* bfp = (const float*)d_in[2];
  const float* Wb = (const float*)d_in[3];
  const float* bbp = (const float*)d_in[4];
  float* out = (float*)d_out;
  char* ws = (char*)d_ws;

  size_t off = 0;
  auto alloc = [&](size_t bytes) {
    char* p = ws + off;
    off = (off + bytes + 255) & ~(size_t)255;
    return p;
  };
  u16* xbf = (u16*)alloc((size_t)M_ * D_ * 2);             // 64 MB
  u16* wxT = (u16*)alloc((size_t)2 * G4_ * 1024 * 2);      // 16 MB
  u16* whfl = (u16*)alloc((size_t)2 * 64 * 128 * 1024);    // 16 MB frag-linear
  u16* hst = (u16*)alloc((size_t)2 * 2 * B_ * U_ * 2);     // 0.5 MB ping-pong h
  float* cst = (float*)alloc((size_t)2 * B_ * U_ * 4);     // 0.5 MB cell state
  u16* xproj = (u16*)alloc((size_t)2 * B_ * T_ * G4_ * 2); // 512 MB

  hipMemsetAsync(hst, 0, (size_t)2 * 2 * B_ * U_ * 2, stream);
  hipMemsetAsync(cst, 0, (size_t)2 * B_ * U_ * 4, stream);

  cast_x_kernel<<<2048, 256, 0, stream>>>(x, xbf);
  pack_wx_kernel<<<2048, 256, 0, stream>>>(Wf, Wb, wxT);
  pack_whfl_kernel<<<4096, 256, 0, stream>>>(Wf, Wb, whfl);

  dim3 gg(M_ / 128, G4_ / 128, 2);
  gemm_xproj3<<<gg, 256, 0, stream>>>(xbf, wxT, bfp, bbp, xproj);

  for (int s = 0; s < T_; ++s) {
    const u16* hr = hst + (size_t)(s & 1) * 2 * B_ * U_;
    u16* hw = hst + (size_t)((s + 1) & 1) * 2 * B_ * U_;
    lstm_step8<<<dim3(128, 2), 256, 0, stream>>>(whfl, xproj, hr, hw, cst, out, s);
  }
}